// Round 5
// baseline (85.771 us; speedup 1.0000x reference)
//
#include <hip/hip_runtime.h>
#include <stdint.h>

// AdaMoLE single fused kernel, bf16 MFMA. 16 tok/block, grid 512 (2 blocks/CU).
//  N=8192 tokens, D_IN=4096, D_OUT=4096, E=8, r=16, SCALING=2.0, MAX_THR=1/8.
//  R5: explicit register software-pipelining of W1p/B2p fragment loads
//      (R4 counters: all pipes idle @44 VGPR -> L2-latency-bound).
//
//  ws layout (frag-major packed weights; a wave's MFMA B-fragment = one
//  contiguous 1KB load = uint4 per lane):
//   W1p : [ct=9][k32=128][lane=64] x 16B   rows ct*16+(l&15): 0..127 lora_A
//         (row=e*16+r), 128..135 router_w, 136 thr_w, 137..143 zero. 1,179,648 B
//   B2p : [ct=256][ks=4][lane=64] x 16B    col ct*16+(l&15), k=ks*32+(l>>4)*8,
//         value lora_B[k>>4][col][k&15] * 2.0 (SCALING folded).     1,048,576 B

typedef __bf16 bf16x8 __attribute__((ext_vector_type(8)));
typedef float f32x4 __attribute__((ext_vector_type(4)));

__device__ __forceinline__ f32x4 mfma16(bf16x8 a, bf16x8 b, f32x4 c) {
  return __builtin_amdgcn_mfma_f32_16x16x32_bf16(a, b, c, 0, 0, 0);
}
__device__ __forceinline__ uint32_t bfbits(float f) {
  uint32_t u = __builtin_bit_cast(uint32_t, f);
  return (u + 0x7fffu + ((u >> 16) & 1u)) >> 16;
}
__device__ __forceinline__ uint32_t pk2(float a, float b) {
  return bfbits(a) | (bfbits(b) << 16);
}

// ---------------- pack W1 frag-major
__global__ void pack_w1p(const float* __restrict__ rw, const float* __restrict__ tw,
                         const float* __restrict__ la, uint4* __restrict__ W1p) {
  int id = blockIdx.x * 256 + threadIdx.x;            // 9*128*64 = 73728
  int lane = id & 63, k32 = (id >> 6) & 127, ct = id >> 13;
  int row = ct * 16 + (lane & 15);
  int col = k32 * 32 + (lane >> 4) * 8;
  const float* src = nullptr;
  if (row < 128)      src = la + (size_t)row * 4096 + col;
  else if (row < 136) src = rw + (size_t)(row - 128) * 4096 + col;
  else if (row == 136) src = tw + col;
  float v[8];
#pragma unroll
  for (int j = 0; j < 8; ++j) v[j] = src ? src[j] : 0.f;
  uint4 u;
  u.x = pk2(v[0], v[1]); u.y = pk2(v[2], v[3]);
  u.z = pk2(v[4], v[5]); u.w = pk2(v[6], v[7]);
  W1p[(size_t)(ct * 128 + k32) * 64 + lane] = u;
}

// ---------------- pack B2 frag-major (SCALING=2 folded)
__global__ void pack_b2p(const float* __restrict__ lb, uint4* __restrict__ B2p) {
  int id = blockIdx.x * 256 + threadIdx.x;            // 256*4*64 = 65536
  int lane = id & 63, ks = (id >> 6) & 3, ct = id >> 8;
  int o = ct * 16 + (lane & 15);
  int k0 = ks * 32 + (lane >> 4) * 8;                 // k0&15 in {0,8}: 8 floats same (e,o)
  const float* s = lb + (size_t)(k0 >> 4) * 65536 + (size_t)o * 16 + (k0 & 15);
  uint4 u;
  u.x = pk2(s[0] * 2.f, s[1] * 2.f); u.y = pk2(s[2] * 2.f, s[3] * 2.f);
  u.z = pk2(s[4] * 2.f, s[5] * 2.f); u.w = pk2(s[6] * 2.f, s[7] * 2.f);
  B2p[(size_t)(ct * 4 + ks) * 64 + lane] = u;
}

// ---------------- fused: gating + h + out. 16 tok/block, 8 waves, grid 512.
__global__ __launch_bounds__(512, 4) void k_fused(
    const float* __restrict__ inp, const uint4* __restrict__ W1p,
    const uint4* __restrict__ B2p, const float* __restrict__ rb,
    const float* __restrict__ tb, float* __restrict__ out) {
  // [0,33024): phase1 A dbuf (2x16KB) / epi partials (8KB) / phase2 bounce
  //            (16 rows x 2064B). [33024,+4K): whl bf16 [16][128] swizzled.
  // [37120,+1K): scores[16][16]. [38144,+512): wgt[16][8].
  __shared__ __align__(16) char smem[38656];
  char* const Ab  = smem;
  char* const whl = smem + 33024;
  float* const scores = (float*)(smem + 37120);
  float* const wgt    = (float*)(smem + 38144);

  const int t = threadIdx.x;
  const int lane = t & 63;
  const int w = t >> 6;
  const int l15 = lane & 15;
  const int lq = lane >> 4;
  const int n0 = blockIdx.x * 16;
  const int rx = (l15 & 7) << 4;

  // ===== phase 1: C[16 tok][144] over K=4096, 8 chunks of 512 (16 groups).
  // wave w owns col-tile w; tile 8 (gating) K-split across waves.
  const int srow = t >> 5;                 // A staging row (0..15)
  const float* ap = inp + (size_t)(n0 + srow) * 4096 + (t & 31) * 4;
  const int sx = (srow & 7) << 4;

  f32x4 accO0 = {}, accO1 = {};
  f32x4 acc8 = {};
  float4 av[4];

  const uint4* wbase  = W1p + (size_t)(w * 128) * 64 + lane;   // own col-tile
  const uint4* w8base = W1p + (size_t)(8 * 128) * 64 + lane;   // gating tile

  // issue W-fragment group g (c=g>>1, h=g&1): 8 own frags + 1 tile-8 frag
#define ISSUE_W(WB, W8R, g) do {                                          \
    const int c_ = (g) >> 1, h_ = (g) & 1;                                \
    const uint4* p_ = wbase + (size_t)(c_ * 16 + h_ * 8) * 64;            \
    _Pragma("unroll")                                                     \
    for (int j_ = 0; j_ < 8; ++j_) WB[j_] = p_[(size_t)j_ * 64];          \
    W8R = w8base[(size_t)(c_ * 16 + w + h_ * 8) * 64];                    \
  } while (0)

  // compute group: 8 own MFMAs (split acc for ILP) + 1 gating MFMA
#define COMPUTE_G(WB, W8R, A0, h_) do {                                   \
    _Pragma("unroll")                                                     \
    for (int j_ = 0; j_ < 8; ++j_) {                                      \
      const int ks_ = (h_) * 8 + j_;                                      \
      bf16x8 a_ = *(const bf16x8*)((A0) + l15 * 1024 + ((ks_ * 64 + lq * 16) ^ rx)); \
      if (j_ & 1) accO1 = mfma16(a_, __builtin_bit_cast(bf16x8, WB[j_]), accO1);     \
      else        accO0 = mfma16(a_, __builtin_bit_cast(bf16x8, WB[j_]), accO0);     \
    }                                                                     \
    {                                                                     \
      const int ks8_ = w + (h_) * 8;                                      \
      bf16x8 a8_ = *(const bf16x8*)((A0) + l15 * 1024 + ((ks8_ * 64 + lq * 16) ^ rx)); \
      acc8 = mfma16(a8_, __builtin_bit_cast(bf16x8, W8R), acc8);          \
    }                                                                     \
  } while (0)

  // stage chunk 0 into buf 0
#pragma unroll
  for (int j = 0; j < 4; ++j) av[j] = *(const float4*)(ap + j * 128);
  {
    char* d2 = Ab + srow * 1024;
#pragma unroll
    for (int j = 0; j < 4; ++j) {
      uint2 u; u.x = pk2(av[j].x, av[j].y); u.y = pk2(av[j].z, av[j].w);
      *(uint2*)(d2 + (((t & 31) * 8 + j * 256) ^ sx)) = u;
    }
  }
  uint4 wA[8], wB[8], w8A, w8B;
  ISSUE_W(wA, w8A, 0);
  __syncthreads();

  for (int c = 0; c < 8; ++c) {
    const char* A0 = Ab + (c & 1) * 16384;
    if (c < 7) {  // next-chunk A global loads first (longest latency)
#pragma unroll
      for (int j = 0; j < 4; ++j)
        av[j] = *(const float4*)(ap + (c + 1) * 512 + j * 128);
    }
    ISSUE_W(wB, w8B, 2 * c + 1);
    COMPUTE_G(wA, w8A, A0, 0);
    if (c < 7) {
      ISSUE_W(wA, w8A, 2 * c + 2);
      // A -> other LDS buffer (issued early so ds_writes drain before barrier)
      char* d2 = Ab + ((c & 1) ^ 1) * 16384 + srow * 1024;
#pragma unroll
      for (int j = 0; j < 4; ++j) {
        uint2 u; u.x = pk2(av[j].x, av[j].y); u.y = pk2(av[j].z, av[j].w);
        *(uint2*)(d2 + (((t & 31) * 8 + j * 256) ^ sx)) = u;
      }
    }
    COMPUTE_G(wB, w8B, A0, 1);
    __syncthreads();
  }
  f32x4 accO;
#pragma unroll
  for (int r_ = 0; r_ < 4; ++r_) accO[r_] = accO0[r_] + accO1[r_];

  // ===== phase 2 pass-0 group-0 prefetch (covers the whole gating epilogue)
  const uint4* bpw = B2p + (size_t)(w * 16) * 64 + lane;  // pass stride = 128*64
  uint4 b0[4], b1[4];
#define LOADB(BB, p_, i_) do {                                            \
    const uint4* q_ = bpw + (size_t)((p_) * 128 + (i_) * 4) * 64;         \
    _Pragma("unroll")                                                     \
    for (int ks_ = 0; ks_ < 4; ++ks_) BB[ks_] = q_[(size_t)ks_ * 64];     \
  } while (0)
  LOADB(b0, 0, 0);

  // ===== epilogue: reduce tile-8 partials, gate, build whl
  *(f32x4*)(Ab + (size_t)(w * 64 + lane) * 16) = acc8;
  __syncthreads();
  if (t < 256) {
    const int l = t >> 2, r_ = t & 3;
    float s = 0.f;
#pragma unroll
    for (int w2 = 0; w2 < 8; ++w2)
      s += ((const float*)Ab)[(w2 * 64 + l) * 4 + r_];
    scores[((l >> 4) * 4 + r_) * 16 + (l & 15)] = s;
  }
  __syncthreads();
  if (t < 16) {
    float l_[9];
#pragma unroll
    for (int e = 0; e < 9; ++e) l_[e] = scores[t * 16 + e];
    float mx = -3.4e38f;
#pragma unroll
    for (int e = 0; e < 8; ++e) { l_[e] += rb[e]; mx = fmaxf(mx, l_[e]); }
    float g[8], s = 0.f;
#pragma unroll
    for (int e = 0; e < 8; ++e) { g[e] = __expf(l_[e] - mx); s += g[e]; }
    const float thr = 0.125f / (1.f + __expf(-(l_[8] + tb[0])));
    const float inv = 1.f / s;
    float wv[8], ws = 0.f;
#pragma unroll
    for (int e = 0; e < 8; ++e) { wv[e] = fmaxf(g[e] * inv - thr, 0.f); ws += wv[e]; }
    const float wn = (ws == 0.f) ? 1.f : ws;
#pragma unroll
    for (int e = 0; e < 8; ++e) wgt[t * 8 + e] = wv[e] / wn;
  }
  __syncthreads();
  // weighted h -> whl (wave w == expert w), swizzled by token
#pragma unroll
  for (int r_ = 0; r_ < 4; ++r_) {
    const int tok = lq * 4 + r_;
    *(unsigned short*)(whl + tok * 256 + (((w * 16 + l15) * 2) ^ ((tok & 7) << 4))) =
        (unsigned short)bfbits(accO[r_] * wgt[tok * 8 + w]);
  }
  __syncthreads();

  // ===== phase 2: out[16 tok][4096] = whl @ B2p^T, 8 passes of 512 cols.
  // swapped MFMA: lane's 4 acc regs = 4 consecutive out cols; token = l15.
  bf16x8 pa[4];
#pragma unroll
  for (int ks = 0; ks < 4; ++ks)
    pa[ks] = *(const bf16x8*)(whl + l15 * 256 + ((ks * 64 + lq * 16) ^ rx));

  const int row = t >> 5, seg = t & 31;    // store: 32 segs x 4 j per row
  float* orow = out + (size_t)(n0 + row) * 4096 + seg * 4;
  for (int p = 0; p < 8; ++p) {
    f32x4 acc[4] = {};
    LOADB(b1, p, 1);
#pragma unroll
    for (int ks = 0; ks < 4; ++ks)
      acc[0] = mfma16(__builtin_bit_cast(bf16x8, b0[ks]), pa[ks], acc[0]);
    LOADB(b0, p, 2);
#pragma unroll
    for (int ks = 0; ks < 4; ++ks)
      acc[1] = mfma16(__builtin_bit_cast(bf16x8, b1[ks]), pa[ks], acc[1]);
    LOADB(b1, p, 3);
#pragma unroll
    for (int ks = 0; ks < 4; ++ks)
      acc[2] = mfma16(__builtin_bit_cast(bf16x8, b0[ks]), pa[ks], acc[2]);
    if (p < 7) LOADB(b0, p + 1, 0);
#pragma unroll
    for (int ks = 0; ks < 4; ++ks)
      acc[3] = mfma16(__builtin_bit_cast(bf16x8, b1[ks]), pa[ks], acc[3]);
    // bounce -> LDS [tok][512 f32], padded row stride 2064B
#pragma unroll
    for (int i = 0; i < 4; ++i)
      *(f32x4*)(Ab + l15 * 2064 + (w * 4 + i) * 64 + lq * 16) = acc[i];
    asm volatile("s_waitcnt lgkmcnt(0)" ::: "memory");
    __builtin_amdgcn_sched_barrier(0);
    __builtin_amdgcn_s_barrier();          // LDS-only barrier: stores keep streaming
#pragma unroll
    for (int j = 0; j < 4; ++j) {
      f32x4 v = *(const f32x4*)(Ab + row * 2064 + (seg + j * 32) * 16);
      __builtin_nontemporal_store(v, (f32x4*)(orow + p * 512 + j * 128));
    }
    asm volatile("s_waitcnt lgkmcnt(0)" ::: "memory");
    __builtin_amdgcn_sched_barrier(0);
    __builtin_amdgcn_s_barrier();
  }
#undef ISSUE_W
#undef COMPUTE_G
#undef LOADB
}

extern "C" void kernel_launch(void* const* d_in, const int* in_sizes, int n_in,
                              void* d_out, int out_size, void* d_ws, size_t ws_size,
                              hipStream_t stream) {
  (void)in_sizes; (void)n_in; (void)out_size; (void)ws_size;
  const float* inp      = (const float*)d_in[0];
  const float* router_w = (const float*)d_in[1];
  const float* router_b = (const float*)d_in[2];
  const float* thr_w    = (const float*)d_in[3];
  const float* thr_b    = (const float*)d_in[4];
  const float* lora_A   = (const float*)d_in[5];
  const float* lora_B   = (const float*)d_in[6];
  float* out = (float*)d_out;

  char* ws = (char*)d_ws;
  uint4* W1p = (uint4*)ws;                      // 1,179,648 B
  uint4* B2p = (uint4*)(ws + 1179648);          // 1,048,576 B

  pack_w1p<<<288, 256, 0, stream>>>(router_w, thr_w, lora_A, W1p);
  pack_b2p<<<256, 256, 0, stream>>>(lora_B, B2p);
  k_fused<<<512, 512, 0, stream>>>(inp, W1p, B2p, router_b, thr_b, out);
}

// Round 7
// 78.768 us; speedup vs baseline: 1.0889x; 1.0889x over previous
//
#include <hip/hip_runtime.h>
#include <stdint.h>

// AdaMoLE R7 — bisect round.
//  k1_gate: Round-4's PROVEN fused phase-1+gating (16 tok/block, grid 512),
//           phase 2 replaced by coalesced global wh write (R2's proven tail).
//  k2_out : R6's NEW kernel (B2p->LDS once per block + swizzled Ob bounce).
//  Only k2_out is unproven. PASS => R6 bug was in K-split k1_h/k1b path.
//
//  ws: W1p frag-major 1,179,648 B | B2p frag-major 1,048,576 B | wh 2 MB
//  wh[tok][128] bf16 rows carry the (tok&7)<<4 byte-XOR swizzle (copied
//  verbatim from whl); k2_out unswizzles via uint4-idx XOR (l15&7).

typedef __bf16 bf16x8 __attribute__((ext_vector_type(8)));
typedef float f32x4 __attribute__((ext_vector_type(4)));
typedef __attribute__((address_space(1))) const void* gp_t;
typedef __attribute__((address_space(3))) void* lp_t;

__device__ __forceinline__ f32x4 mfma16(bf16x8 a, bf16x8 b, f32x4 c) {
  return __builtin_amdgcn_mfma_f32_16x16x32_bf16(a, b, c, 0, 0, 0);
}
__device__ __forceinline__ uint32_t bfbits(float f) {
  uint32_t u = __builtin_bit_cast(uint32_t, f);
  return (u + 0x7fffu + ((u >> 16) & 1u)) >> 16;
}
__device__ __forceinline__ uint32_t pk2(float a, float b) {
  return bfbits(a) | (bfbits(b) << 16);
}

// ---------------- pack W1 frag-major: rows ct*16+(l&15): 0..127 lora_A
// (row=e*16+r), 128..135 router_w, 136 thr_w, 137..143 zero.
__global__ void pack_w1p(const float* __restrict__ rw, const float* __restrict__ tw,
                         const float* __restrict__ la, uint4* __restrict__ W1p) {
  int id = blockIdx.x * 256 + threadIdx.x;            // 9*128*64 = 73728
  int lane = id & 63, k32 = (id >> 6) & 127, ct = id >> 13;
  int row = ct * 16 + (lane & 15);
  int col = k32 * 32 + (lane >> 4) * 8;
  const float* src = nullptr;
  if (row < 128)      src = la + (size_t)row * 4096 + col;
  else if (row < 136) src = rw + (size_t)(row - 128) * 4096 + col;
  else if (row == 136) src = tw + col;
  float v[8];
#pragma unroll
  for (int j = 0; j < 8; ++j) v[j] = src ? src[j] : 0.f;
  uint4 u;
  u.x = pk2(v[0], v[1]); u.y = pk2(v[2], v[3]);
  u.z = pk2(v[4], v[5]); u.w = pk2(v[6], v[7]);
  W1p[(size_t)(ct * 128 + k32) * 64 + lane] = u;
}

// ---------------- pack B2 frag-major (SCALING=2 folded)
__global__ void pack_b2p(const float* __restrict__ lb, uint4* __restrict__ B2p) {
  int id = blockIdx.x * 256 + threadIdx.x;            // 256*4*64 = 65536
  int lane = id & 63, ks = (id >> 6) & 3, ct = id >> 8;
  int o = ct * 16 + (lane & 15);
  int k0 = ks * 32 + (lane >> 4) * 8;
  const float* s = lb + (size_t)(k0 >> 4) * 65536 + (size_t)o * 16 + (k0 & 15);
  uint4 u;
  u.x = pk2(s[0] * 2.f, s[1] * 2.f); u.y = pk2(s[2] * 2.f, s[3] * 2.f);
  u.z = pk2(s[4] * 2.f, s[5] * 2.f); u.w = pk2(s[6] * 2.f, s[7] * 2.f);
  B2p[(size_t)(ct * 4 + ks) * 64 + lane] = u;
}

// ---------------- k1_gate: Round-4's k_fused, phase 2 -> wh global write.
// 16 tok/block, 8 waves, grid 512 (2 blocks/CU).
__global__ __launch_bounds__(512, 4) void k1_gate(
    const float* __restrict__ inp, const uint4* __restrict__ W1p,
    const float* __restrict__ rb, const float* __restrict__ tb,
    unsigned short* __restrict__ wh) {
  // [0,32768): phase1 A dbuf (2x16KB) / epi partials (8KB).
  // [33024,+4K): whl bf16 [16][128] swizzled. [37120,+1K): scores. [38144,+512): wgt.
  __shared__ __align__(16) char smem[38656];
  char* const Ab  = smem;
  char* const whl = smem + 33024;
  float* const scores = (float*)(smem + 37120);
  float* const wgt    = (float*)(smem + 38144);

  const int t = threadIdx.x;
  const int lane = t & 63;
  const int w = t >> 6;
  const int l15 = lane & 15;
  const int lq = lane >> 4;
  const int n0 = blockIdx.x * 16;
  const int rx = (l15 & 7) << 4;

  // ===== phase 1: C[16 tok][144] over K=4096, 8 chunks of 512.
  // wave w owns col-tile w; tile 8 (gating) K-split across waves.
  const int srow = t >> 5;                 // A staging row (0..15)
  const float* ap = inp + (size_t)(n0 + srow) * 4096 + (t & 31) * 4;
  const int sx = (srow & 7) << 4;

  f32x4 accO = {};
  f32x4 acc8 = {};
  float4 av[4];

#pragma unroll
  for (int j = 0; j < 4; ++j) av[j] = *(const float4*)(ap + j * 128);
  {
    char* d2 = Ab + srow * 1024;
#pragma unroll
    for (int j = 0; j < 4; ++j) {
      uint2 u; u.x = pk2(av[j].x, av[j].y); u.y = pk2(av[j].z, av[j].w);
      *(uint2*)(d2 + (((t & 31) * 8 + j * 256) ^ sx)) = u;
    }
  }
  __syncthreads();

  for (int c = 0; c < 8; ++c) {
    const int buf = c & 1;
    if (c < 7) {
#pragma unroll
      for (int j = 0; j < 4; ++j)
        av[j] = *(const float4*)(ap + (c + 1) * 512 + j * 128);
    }
    const char* A0 = Ab + buf * 16384;
    const uint4* wown = W1p + (size_t)(w * 128 + c * 16) * 64 + lane;
#pragma unroll
    for (int ks = 0; ks < 16; ++ks) {
      bf16x8 b = __builtin_bit_cast(bf16x8, wown[(size_t)ks * 64]);
      bf16x8 a = *(const bf16x8*)(A0 + l15 * 1024 + ((ks * 64 + lq * 16) ^ rx));
      accO = mfma16(a, b, accO);
    }
    const uint4* w8 = W1p + (size_t)(8 * 128 + c * 16) * 64 + lane;
#pragma unroll
    for (int ii = 0; ii < 2; ++ii) {
      const int ks8 = w + ii * 8;          // K-split of tile 8 across waves
      bf16x8 b8 = __builtin_bit_cast(bf16x8, w8[(size_t)ks8 * 64]);
      bf16x8 a = *(const bf16x8*)(A0 + l15 * 1024 + ((ks8 * 64 + lq * 16) ^ rx));
      acc8 = mfma16(a, b8, acc8);
    }
    if (c < 7) {
      char* d2 = Ab + (buf ^ 1) * 16384 + srow * 1024;
#pragma unroll
      for (int j = 0; j < 4; ++j) {
        uint2 u; u.x = pk2(av[j].x, av[j].y); u.y = pk2(av[j].z, av[j].w);
        *(uint2*)(d2 + (((t & 31) * 8 + j * 256) ^ sx)) = u;
      }
    }
    __syncthreads();
  }

  // ===== epilogue: reduce tile-8 partials, gate, build whl
  *(f32x4*)(Ab + (size_t)(w * 64 + lane) * 16) = acc8;
  __syncthreads();
  if (t < 256) {
    const int l = t >> 2, r_ = t & 3;
    float s = 0.f;
#pragma unroll
    for (int w2 = 0; w2 < 8; ++w2)
      s += ((const float*)Ab)[(w2 * 64 + l) * 4 + r_];
    scores[((l >> 4) * 4 + r_) * 16 + (l & 15)] = s;
  }
  __syncthreads();
  if (t < 16) {
    float l_[9];
#pragma unroll
    for (int e = 0; e < 9; ++e) l_[e] = scores[t * 16 + e];
    float mx = -3.4e38f;
#pragma unroll
    for (int e = 0; e < 8; ++e) { l_[e] += rb[e]; mx = fmaxf(mx, l_[e]); }
    float g[8], s = 0.f;
#pragma unroll
    for (int e = 0; e < 8; ++e) { g[e] = __expf(l_[e] - mx); s += g[e]; }
    const float thr = 0.125f / (1.f + __expf(-(l_[8] + tb[0])));
    const float inv = 1.f / s;
    float wv[8], ws = 0.f;
#pragma unroll
    for (int e = 0; e < 8; ++e) { wv[e] = fmaxf(g[e] * inv - thr, 0.f); ws += wv[e]; }
    const float wn = (ws == 0.f) ? 1.f : ws;
#pragma unroll
    for (int e = 0; e < 8; ++e) wgt[t * 8 + e] = wv[e] / wn;
  }
  __syncthreads();
  // weighted h -> whl (wave w == expert w), swizzled by token
#pragma unroll
  for (int r_ = 0; r_ < 4; ++r_) {
    const int tok = lq * 4 + r_;
    *(unsigned short*)(whl + tok * 256 + (((w * 16 + l15) * 2) ^ ((tok & 7) << 4))) =
        (unsigned short)bfbits(accO[r_] * wgt[tok * 8 + w]);
  }
  __syncthreads();
  // coalesced wh write (R2's proven tail): rows copied byte-verbatim,
  // so global wh keeps the (tok&7)<<4 swizzle. n0 % 16 == 0 => key is tok&7.
  if (t < 256) {
    const int row = t >> 4, seg = t & 15;
    ((uint4*)(wh + (size_t)(n0 + row) * 128))[seg] =
        ((const uint4*)(whl + row * 256))[seg];
  }
}

// ---------------- k2_out: out[256 tok][128 col] per block, grid 1024 =
// 32 tok-grps x 32 col-grps, 512 thr. B2p slice staged ONCE to LDS (32 KB,
// shared by all waves); output bounced via swizzled LDS -> 128B-contiguous
// x rows nontemporal stores. pa read unswizzles wh via uint4-idx XOR.
__global__ __launch_bounds__(512, 4) void k2_out(
    const unsigned short* __restrict__ wh, const uint4* __restrict__ B2p,
    float* __restrict__ out) {
  __shared__ __align__(16) char Bl[32768];
  __shared__ __align__(16) char Ob[32768];
  const int t = threadIdx.x, lane = t & 63, w = t >> 6;
  const int l15 = lane & 15, lq = lane >> 4;
  const int bid = blockIdx.x;
  const int tokg = bid >> 5, colg = bid & 31;
  const int n0 = tokg * 256, c0 = colg * 128;

  {  // stage B slice: 8 ct x 4 ks x 64 lanes x 16B = 32 KB, linear
    const uint4* src = B2p + (size_t)(colg * 32) * 64;
#pragma unroll
    for (int i = 0; i < 4; ++i)
      __builtin_amdgcn_global_load_lds((gp_t)(const void*)(src + i * 512 + t),
          (lp_t)(void*)(Bl + (i * 512 + w * 64) * 16), 16, 0, 0);
  }
  __syncthreads();

  const int srow = t >> 3, sseg = t & 7;       // store map: 64 rows x 8 segs
  const int swz = (srow & 7) << 4;

#pragma unroll
  for (int tt = 0; tt < 2; ++tt) {
    const int tok = n0 + tt * 128 + w * 16 + l15;
    bf16x8 pa[4];
    const uint4* whu = (const uint4*)wh + (size_t)tok * 16;
#pragma unroll
    for (int ks = 0; ks < 4; ++ks)
      pa[ks] = __builtin_bit_cast(bf16x8, whu[(ks * 4 + lq) ^ (l15 & 7)]);
    f32x4 acc[8] = {};
#pragma unroll
    for (int ct = 0; ct < 8; ++ct)
#pragma unroll
      for (int ks = 0; ks < 4; ++ks) {
        bf16x8 b = *(const bf16x8*)(Bl + (size_t)((ct * 4 + ks) * 64 + lane) * 16);
        acc[ct] = mfma16(b, pa[ks], acc[ct]);  // swapped: 4 consecutive cols/lane
      }
    // two subrounds of 64 toks each: waves 4sr..4sr+3 own subround sr
#pragma unroll
    for (int sr = 0; sr < 2; ++sr) {
      if ((w >> 2) == sr) {
        const int tl = (w & 3) * 16 + l15;     // 0..63
        char* d = Ob + tl * 512;
#pragma unroll
        for (int ct = 0; ct < 8; ++ct)
          *(f32x4*)(d + ((ct * 64 + lq * 16) ^ ((tl & 7) << 4))) = acc[ct];
      }
      __syncthreads();
      {
        float* op = out + (size_t)(n0 + tt * 128 + sr * 64 + srow) * 4096 + c0 + sseg * 4;
#pragma unroll
        for (int j = 0; j < 4; ++j) {
          f32x4 v = *(const f32x4*)(Ob + srow * 512 + ((sseg * 16 + j * 128) ^ swz));
          __builtin_nontemporal_store(v, (f32x4*)(op + j * 32));
        }
      }
      __syncthreads();
    }
  }
}

extern "C" void kernel_launch(void* const* d_in, const int* in_sizes, int n_in,
                              void* d_out, int out_size, void* d_ws, size_t ws_size,
                              hipStream_t stream) {
  (void)in_sizes; (void)n_in; (void)out_size; (void)ws_size;
  const float* inp      = (const float*)d_in[0];
  const float* router_w = (const float*)d_in[1];
  const float* router_b = (const float*)d_in[2];
  const float* thr_w    = (const float*)d_in[3];
  const float* thr_b    = (const float*)d_in[4];
  const float* lora_A   = (const float*)d_in[5];
  const float* lora_B   = (const float*)d_in[6];
  float* out = (float*)d_out;

  char* ws = (char*)d_ws;
  uint4*          W1p = (uint4*)ws;                                // 1,179,648 B
  uint4*          B2p = (uint4*)(ws + 1179648);                    // 1,048,576 B
  unsigned short* wh  = (unsigned short*)(ws + 1179648 + 1048576); // 2,097,152 B

  pack_w1p<<<288, 256, 0, stream>>>(router_w, thr_w, lora_A, W1p);
  pack_b2p<<<256, 256, 0, stream>>>(lora_B, B2p);
  k1_gate<<<512, 512, 0, stream>>>(inp, W1p, router_b, thr_b, wh);
  k2_out<<<1024, 512, 0, stream>>>(wh, B2p, out);
}

// Round 8
// 71.033 us; speedup vs baseline: 1.2075x; 1.1089x over previous
//
#include <hip/hip_runtime.h>
#include <stdint.h>

// AdaMoLE R8.
//  k1_gate: 32 tok/block, 1024 thr (16 waves), grid 256. Wave w = col-tile
//           (w&7), K-chunks [(w>>3)*4,+4), BOTH token-tiles per W-frag load
//           -> each W1p fragment read ONCE per block (per-CU L2 traffic
//           2.9 -> 1.7 MB vs R7). Pair-reduce + 16-way gating reduce in LDS.
//  k2_out : R7's PROVEN kernel, unchanged.
//
//  ws: W1p frag-major 1,179,648 B | B2p frag-major 1,048,576 B | wh 2 MB
//  wh[tok][128] bf16 rows carry the (tok&7)<<4 byte-XOR swizzle; k2_out
//  unswizzles via uint4-idx XOR (l15&7).

typedef __bf16 bf16x8 __attribute__((ext_vector_type(8)));
typedef float f32x4 __attribute__((ext_vector_type(4)));
typedef __attribute__((address_space(1))) const void* gp_t;
typedef __attribute__((address_space(3))) void* lp_t;

__device__ __forceinline__ f32x4 mfma16(bf16x8 a, bf16x8 b, f32x4 c) {
  return __builtin_amdgcn_mfma_f32_16x16x32_bf16(a, b, c, 0, 0, 0);
}
__device__ __forceinline__ uint32_t bfbits(float f) {
  uint32_t u = __builtin_bit_cast(uint32_t, f);
  return (u + 0x7fffu + ((u >> 16) & 1u)) >> 16;
}
__device__ __forceinline__ uint32_t pk2(float a, float b) {
  return bfbits(a) | (bfbits(b) << 16);
}

// ---------------- pack W1 frag-major: rows ct*16+(l&15): 0..127 lora_A
// (row=e*16+r), 128..135 router_w, 136 thr_w, 137..143 zero.
__global__ void pack_w1p(const float* __restrict__ rw, const float* __restrict__ tw,
                         const float* __restrict__ la, uint4* __restrict__ W1p) {
  int id = blockIdx.x * 256 + threadIdx.x;            // 9*128*64 = 73728
  int lane = id & 63, k32 = (id >> 6) & 127, ct = id >> 13;
  int row = ct * 16 + (lane & 15);
  int col = k32 * 32 + (lane >> 4) * 8;
  const float* src = nullptr;
  if (row < 128)      src = la + (size_t)row * 4096 + col;
  else if (row < 136) src = rw + (size_t)(row - 128) * 4096 + col;
  else if (row == 136) src = tw + col;
  float v[8];
#pragma unroll
  for (int j = 0; j < 8; ++j) v[j] = src ? src[j] : 0.f;
  uint4 u;
  u.x = pk2(v[0], v[1]); u.y = pk2(v[2], v[3]);
  u.z = pk2(v[4], v[5]); u.w = pk2(v[6], v[7]);
  W1p[(size_t)(ct * 128 + k32) * 64 + lane] = u;
}

// ---------------- pack B2 frag-major (SCALING=2 folded)
__global__ void pack_b2p(const float* __restrict__ lb, uint4* __restrict__ B2p) {
  int id = blockIdx.x * 256 + threadIdx.x;            // 256*4*64 = 65536
  int lane = id & 63, ks = (id >> 6) & 3, ct = id >> 8;
  int o = ct * 16 + (lane & 15);
  int k0 = ks * 32 + (lane >> 4) * 8;
  const float* s = lb + (size_t)(k0 >> 4) * 65536 + (size_t)o * 16 + (k0 & 15);
  uint4 u;
  u.x = pk2(s[0] * 2.f, s[1] * 2.f); u.y = pk2(s[2] * 2.f, s[3] * 2.f);
  u.z = pk2(s[4] * 2.f, s[5] * 2.f); u.w = pk2(s[6] * 2.f, s[7] * 2.f);
  B2p[(size_t)(ct * 4 + ks) * 64 + lane] = u;
}

// ---------------- k1_gate: 32 tok/block, 16 waves, grid 256.
__global__ __launch_bounds__(1024) void k1_gate(
    const float* __restrict__ inp, const uint4* __restrict__ W1p,
    const float* __restrict__ rb, const float* __restrict__ tb,
    unsigned short* __restrict__ wh) {
  // [0,64K): A tile, 2 K-groups x 32 rows x 1024B (single-buffered);
  //          reused for reductions: accO slots [0,32K), acc8 slots [32K,64K).
  // [64K,+8K): whl bf16 [32][128] swizzled. [73728,+2K): scores[32][16].
  // [75776,+512): wgt[32][8].
  __shared__ __align__(16) char smem[76288];
  char* const Ab  = smem;
  char* const whl = smem + 65536;
  float* const scores = (float*)(smem + 73728);
  float* const wgt    = (float*)(smem + 75776);

  const int t = threadIdx.x;           // 0..1023
  const int lane = t & 63;
  const int w = t >> 6;                // 0..15
  const int kg = w >> 3;               // K-group: chunks [kg*4, kg*4+4)
  const int ct_ = w & 7;               // col-tile
  const int l15 = lane & 15;
  const int lq = lane >> 4;
  const int n0 = blockIdx.x * 32;
  const int rx = (l15 & 7) << 4;

  // A staging: 1024 thr = 32 rows x 32 col-groups; pair {c, c+4} per iter.
  const int srow = t >> 5;             // 0..31
  const int scf = t & 31;              // fp32 cols scf*4 + j*128
  const float* ap = inp + (size_t)(n0 + srow) * 4096 + scf * 4;
  const int sx = (srow & 7) << 4;

  f32x4 accO[2] = {}, acc8[2] = {};
  float4 av[2][4];

  const uint4* wown = W1p + (size_t)(ct_ * 128) * 64 + lane;
  const uint4* w8b  = W1p + (size_t)(8 * 128) * 64 + lane;

  // ---- prologue: stage pair {0, 4}
#pragma unroll
  for (int g = 0; g < 2; ++g)
#pragma unroll
    for (int j = 0; j < 4; ++j)
      av[g][j] = *(const float4*)(ap + (size_t)(g * 4) * 512 + j * 128);
#pragma unroll
  for (int g = 0; g < 2; ++g) {
    char* d2 = Ab + g * 32768 + srow * 1024;
#pragma unroll
    for (int j = 0; j < 4; ++j) {
      uint2 u; u.x = pk2(av[g][j].x, av[g][j].y); u.y = pk2(av[g][j].z, av[g][j].w);
      *(uint2*)(d2 + ((scf * 8 + j * 256) ^ sx)) = u;
    }
  }
  __syncthreads();

  for (int c = 0; c < 4; ++c) {
    if (c < 3) {  // prefetch next pair {c+1, c+5} into registers
#pragma unroll
      for (int g = 0; g < 2; ++g)
#pragma unroll
        for (int j = 0; j < 4; ++j)
          av[g][j] = *(const float4*)(ap + (size_t)(g * 4 + c + 1) * 512 + j * 128);
    }
    const int ck = kg * 4 + c;         // this wave's K-chunk
    const char* A0 = Ab + kg * 32768;
#pragma unroll
    for (int ks = 0; ks < 16; ++ks) {
      bf16x8 b = __builtin_bit_cast(bf16x8, wown[(size_t)(ck * 16 + ks) * 64]);
      bf16x8 a0 = *(const bf16x8*)(A0 + l15 * 1024 + ((ks * 64 + lq * 16) ^ rx));
      bf16x8 a1 = *(const bf16x8*)(A0 + (16 + l15) * 1024 + ((ks * 64 + lq * 16) ^ rx));
      accO[0] = mfma16(a0, b, accO[0]);
      accO[1] = mfma16(a1, b, accO[1]);
    }
#pragma unroll
    for (int ii = 0; ii < 2; ++ii) {   // gating tile-8, ks split by col-tile
      const int ks8 = ct_ + ii * 8;
      bf16x8 b8 = __builtin_bit_cast(bf16x8, w8b[(size_t)(ck * 16 + ks8) * 64]);
      bf16x8 a0 = *(const bf16x8*)(A0 + l15 * 1024 + ((ks8 * 64 + lq * 16) ^ rx));
      bf16x8 a1 = *(const bf16x8*)(A0 + (16 + l15) * 1024 + ((ks8 * 64 + lq * 16) ^ rx));
      acc8[0] = mfma16(a0, b8, acc8[0]);
      acc8[1] = mfma16(a1, b8, acc8[1]);
    }
    if (c < 3) {
      __syncthreads();                 // all reads of Ab done
#pragma unroll
      for (int g = 0; g < 2; ++g) {
        char* d2 = Ab + g * 32768 + srow * 1024;
#pragma unroll
        for (int j = 0; j < 4; ++j) {
          uint2 u; u.x = pk2(av[g][j].x, av[g][j].y); u.y = pk2(av[g][j].z, av[g][j].w);
          *(uint2*)(d2 + ((scf * 8 + j * 256) ^ sx)) = u;
        }
      }
    }
    __syncthreads();                   // writes visible / final fence
  }

  // ---- reductions: accO pair-sum (w, w+8) + acc8 16-way
  *(f32x4*)(Ab + (size_t)((w * 2 + 0) * 64 + lane) * 16) = accO[0];
  *(f32x4*)(Ab + (size_t)((w * 2 + 1) * 64 + lane) * 16) = accO[1];
  *(f32x4*)(Ab + 32768 + (size_t)((w * 2 + 0) * 64 + lane) * 16) = acc8[0];
  *(f32x4*)(Ab + 32768 + (size_t)((w * 2 + 1) * 64 + lane) * 16) = acc8[1];
  __syncthreads();
  f32x4 hO[2] = {};
  if (w < 8) {
#pragma unroll
    for (int tt = 0; tt < 2; ++tt) {
      f32x4 x = *(const f32x4*)(Ab + (size_t)((w * 2 + tt) * 64 + lane) * 16);
      f32x4 y = *(const f32x4*)(Ab + (size_t)(((w + 8) * 2 + tt) * 64 + lane) * 16);
#pragma unroll
      for (int r_ = 0; r_ < 4; ++r_) hO[tt][r_] = x[r_] + y[r_];
    }
  }
  if (t < 512) {  // gating scores: 32 tok x 16 cols
    const int tok = t >> 4, col = t & 15;
    const int tt = tok >> 4, lq_ = (tok >> 2) & 3, r_ = tok & 3;
    float sv = 0.f;
#pragma unroll
    for (int w2 = 0; w2 < 16; ++w2)
      sv += *(const float*)(Ab + 32768 +
            (size_t)((w2 * 2 + tt) * 64 + lq_ * 16 + col) * 16 + r_ * 4);
    scores[tok * 16 + col] = sv;
  }
  __syncthreads();
  if (t < 32) {
    float l_[9];
#pragma unroll
    for (int e = 0; e < 9; ++e) l_[e] = scores[t * 16 + e];
    float mx = -3.4e38f;
#pragma unroll
    for (int e = 0; e < 8; ++e) { l_[e] += rb[e]; mx = fmaxf(mx, l_[e]); }
    float g[8], s = 0.f;
#pragma unroll
    for (int e = 0; e < 8; ++e) { g[e] = __expf(l_[e] - mx); s += g[e]; }
    const float thr = 0.125f / (1.f + __expf(-(l_[8] + tb[0])));
    const float inv = 1.f / s;
    float wv[8], ws = 0.f;
#pragma unroll
    for (int e = 0; e < 8; ++e) { wv[e] = fmaxf(g[e] * inv - thr, 0.f); ws += wv[e]; }
    const float wn = (ws == 0.f) ? 1.f : ws;
#pragma unroll
    for (int e = 0; e < 8; ++e) wgt[t * 8 + e] = wv[e] / wn;
  }
  __syncthreads();
  // weighted h -> whl (wave w<8 == expert w), swizzled by token
  if (w < 8) {
#pragma unroll
    for (int tt = 0; tt < 2; ++tt)
#pragma unroll
      for (int r_ = 0; r_ < 4; ++r_) {
        const int tok = tt * 16 + lq * 4 + r_;
        *(unsigned short*)(whl + tok * 256 + (((w * 16 + l15) * 2) ^ ((tok & 7) << 4))) =
            (unsigned short)bfbits(hO[tt][r_] * wgt[tok * 8 + w]);
      }
  }
  __syncthreads();
  // coalesced wh write: rows copied byte-verbatim (swizzle kept; n0%32==0)
  if (t < 512) {
    const int row = t >> 4, seg = t & 15;
    ((uint4*)(wh + (size_t)(n0 + row) * 128))[seg] =
        ((const uint4*)(whl + row * 256))[seg];
  }
}

// ---------------- k2_out: R7's PROVEN kernel, unchanged. out[256 tok][128
// col] per block, grid 1024, 512 thr. B2p slice staged once to LDS; swizzled
// Ob bounce -> 128B-contiguous nontemporal stores; pa unswizzles wh via
// uint4-idx XOR.
__global__ __launch_bounds__(512, 4) void k2_out(
    const unsigned short* __restrict__ wh, const uint4* __restrict__ B2p,
    float* __restrict__ out) {
  __shared__ __align__(16) char Bl[32768];
  __shared__ __align__(16) char Ob[32768];
  const int t = threadIdx.x, lane = t & 63, w = t >> 6;
  const int l15 = lane & 15, lq = lane >> 4;
  const int bid = blockIdx.x;
  const int tokg = bid >> 5, colg = bid & 31;
  const int n0 = tokg * 256, c0 = colg * 128;

  {  // stage B slice: 8 ct x 4 ks x 64 lanes x 16B = 32 KB, linear
    const uint4* src = B2p + (size_t)(colg * 32) * 64;
#pragma unroll
    for (int i = 0; i < 4; ++i)
      __builtin_amdgcn_global_load_lds((gp_t)(const void*)(src + i * 512 + t),
          (lp_t)(void*)(Bl + (i * 512 + w * 64) * 16), 16, 0, 0);
  }
  __syncthreads();

  const int srow = t >> 3, sseg = t & 7;       // store map: 64 rows x 8 segs
  const int swz = (srow & 7) << 4;

#pragma unroll
  for (int tt = 0; tt < 2; ++tt) {
    const int tok = n0 + tt * 128 + w * 16 + l15;
    bf16x8 pa[4];
    const uint4* whu = (const uint4*)wh + (size_t)tok * 16;
#pragma unroll
    for (int ks = 0; ks < 4; ++ks)
      pa[ks] = __builtin_bit_cast(bf16x8, whu[(ks * 4 + lq) ^ (l15 & 7)]);
    f32x4 acc[8] = {};
#pragma unroll
    for (int ct = 0; ct < 8; ++ct)
#pragma unroll
      for (int ks = 0; ks < 4; ++ks) {
        bf16x8 b = *(const bf16x8*)(Bl + (size_t)((ct * 4 + ks) * 64 + lane) * 16);
        acc[ct] = mfma16(b, pa[ks], acc[ct]);  // swapped: 4 consecutive cols/lane
      }
#pragma unroll
    for (int sr = 0; sr < 2; ++sr) {
      if ((w >> 2) == sr) {
        const int tl = (w & 3) * 16 + l15;     // 0..63
        char* d = Ob + tl * 512;
#pragma unroll
        for (int ct = 0; ct < 8; ++ct)
          *(f32x4*)(d + ((ct * 64 + lq * 16) ^ ((tl & 7) << 4))) = acc[ct];
      }
      __syncthreads();
      {
        float* op = out + (size_t)(n0 + tt * 128 + sr * 64 + srow) * 4096 + c0 + sseg * 4;
#pragma unroll
        for (int j = 0; j < 4; ++j) {
          f32x4 v = *(const f32x4*)(Ob + srow * 512 + ((sseg * 16 + j * 128) ^ swz));
          __builtin_nontemporal_store(v, (f32x4*)(op + j * 32));
        }
      }
      __syncthreads();
    }
  }
}

extern "C" void kernel_launch(void* const* d_in, const int* in_sizes, int n_in,
                              void* d_out, int out_size, void* d_ws, size_t ws_size,
                              hipStream_t stream) {
  (void)in_sizes; (void)n_in; (void)out_size; (void)ws_size;
  const float* inp      = (const float*)d_in[0];
  const float* router_w = (const float*)d_in[1];
  const float* router_b = (const float*)d_in[2];
  const float* thr_w    = (const float*)d_in[3];
  const float* thr_b    = (const float*)d_in[4];
  const float* lora_A   = (const float*)d_in[5];
  const float* lora_B   = (const float*)d_in[6];
  float* out = (float*)d_out;

  char* ws = (char*)d_ws;
  uint4*          W1p = (uint4*)ws;                                // 1,179,648 B
  uint4*          B2p = (uint4*)(ws + 1179648);                    // 1,048,576 B
  unsigned short* wh  = (unsigned short*)(ws + 1179648 + 1048576); // 2,097,152 B

  pack_w1p<<<288, 256, 0, stream>>>(router_w, thr_w, lora_A, W1p);
  pack_b2p<<<256, 256, 0, stream>>>(lora_B, B2p);
  k1_gate<<<256, 1024, 0, stream>>>(inp, W1p, router_b, thr_b, wh);
  k2_out<<<1024, 512, 0, stream>>>(wh, B2p, out);
}

// Round 10
// 66.706 us; speedup vs baseline: 1.2858x; 1.0649x over previous
//
#include <hip/hip_runtime.h>
#include <stdint.h>

// AdaMoLE R10 = R8 (proven 71us) + {merged pack, smem fix, raw LDS barriers}.
//  k1_gate: 32 tok/block, 16 waves, grid 256. Wave w = col-tile (w&7),
//           K-chunks [(w>>3)*4,+4), both token-tiles per W-frag load.
//           Single-buffered A tile (R8's proven sync structure), but in-loop
//           barriers are lgkmcnt-only (global A-prefetch stays in flight).
//  k2_out : R7/R8's proven kernel; Ob-bounce barriers lgkmcnt-only so the
//           nontemporal store stream never drains at a barrier (R3-phase2
//           proven pattern).
//
//  ws: W1p frag-major 1,179,648 B | B2p frag-major 1,048,576 B | wh 2 MB
//  wh[tok][128] bf16 rows carry the (tok&7)<<4 byte-XOR swizzle; k2_out
//  unswizzles via uint4-idx XOR (l15&7).

typedef __bf16 bf16x8 __attribute__((ext_vector_type(8)));
typedef float f32x4 __attribute__((ext_vector_type(4)));
typedef __attribute__((address_space(1))) const void* gp_t;
typedef __attribute__((address_space(3))) void* lp_t;

__device__ __forceinline__ f32x4 mfma16(bf16x8 a, bf16x8 b, f32x4 c) {
  return __builtin_amdgcn_mfma_f32_16x16x32_bf16(a, b, c, 0, 0, 0);
}
__device__ __forceinline__ uint32_t bfbits(float f) {
  uint32_t u = __builtin_bit_cast(uint32_t, f);
  return (u + 0x7fffu + ((u >> 16) & 1u)) >> 16;
}
__device__ __forceinline__ uint32_t pk2(float a, float b) {
  return bfbits(a) | (bfbits(b) << 16);
}

// LDS-only barrier: per-wave ds ops drained (lgkmcnt), execution synced,
// but outstanding GLOBAL loads/stores keep streaming (no vmcnt drain).
// sched_barrier(0) on both sides pins memory ops to their side (rule #18).
#define LDS_BARRIER() do {                                   \
    asm volatile("s_waitcnt lgkmcnt(0)" ::: "memory");       \
    __builtin_amdgcn_sched_barrier(0);                       \
    __builtin_amdgcn_s_barrier();                            \
    __builtin_amdgcn_sched_barrier(0);                       \
  } while (0)

// ---------------- merged pack: blocks [0,288) = W1p, [288,544) = B2p.
// W1p rows ct*16+(l&15): 0..127 lora_A (row=e*16+r), 128..135 router_w,
// 136 thr_w, 137..143 zero. B2p: SCALING=2 folded.
__global__ void pack_all(const float* __restrict__ rw, const float* __restrict__ tw,
                         const float* __restrict__ la, const float* __restrict__ lb,
                         uint4* __restrict__ W1p, uint4* __restrict__ B2p) {
  if (blockIdx.x < 288) {
    int id = blockIdx.x * 256 + threadIdx.x;          // 9*128*64 = 73728
    int lane = id & 63, k32 = (id >> 6) & 127, ct = id >> 13;
    int row = ct * 16 + (lane & 15);
    int col = k32 * 32 + (lane >> 4) * 8;
    const float* src = nullptr;
    if (row < 128)      src = la + (size_t)row * 4096 + col;
    else if (row < 136) src = rw + (size_t)(row - 128) * 4096 + col;
    else if (row == 136) src = tw + col;
    float v[8];
#pragma unroll
    for (int j = 0; j < 8; ++j) v[j] = src ? src[j] : 0.f;
    uint4 u;
    u.x = pk2(v[0], v[1]); u.y = pk2(v[2], v[3]);
    u.z = pk2(v[4], v[5]); u.w = pk2(v[6], v[7]);
    W1p[(size_t)(ct * 128 + k32) * 64 + lane] = u;
  } else {
    int id = (blockIdx.x - 288) * 256 + threadIdx.x;  // 256*4*64 = 65536
    int lane = id & 63, ks = (id >> 6) & 3, ct = id >> 8;
    int o = ct * 16 + (lane & 15);
    int k0 = ks * 32 + (lane >> 4) * 8;
    const float* s = lb + (size_t)(k0 >> 4) * 65536 + (size_t)o * 16 + (k0 & 15);
    uint4 u;
    u.x = pk2(s[0] * 2.f, s[1] * 2.f); u.y = pk2(s[2] * 2.f, s[3] * 2.f);
    u.z = pk2(s[4] * 2.f, s[5] * 2.f); u.w = pk2(s[6] * 2.f, s[7] * 2.f);
    B2p[(size_t)(ct * 4 + ks) * 64 + lane] = u;
  }
}

// ---------------- k1_gate: 32 tok/block, 16 waves, grid 256 (R8 structure).
__global__ __launch_bounds__(1024) void k1_gate(
    const float* __restrict__ inp, const uint4* __restrict__ W1p,
    const float* __restrict__ rb, const float* __restrict__ tb,
    unsigned short* __restrict__ wh) {
  // [0,64K): A tile, 2 K-groups x 32 rows x 1024B (single-buffered);
  //          reused for reductions: accO slots [0,32K), acc8 slots [32K,64K).
  // [64K,+8K): whl bf16 [32][128] swizzled. [73728,+2K): scores[32][16].
  // [75776,+1K): wgt[32][8].
  __shared__ __align__(16) char smem[76800];
  char* const Ab  = smem;
  char* const whl = smem + 65536;
  float* const scores = (float*)(smem + 73728);
  float* const wgt    = (float*)(smem + 75776);

  const int t = threadIdx.x;           // 0..1023
  const int lane = t & 63;
  const int w = t >> 6;                // 0..15
  const int kg = w >> 3;               // K-group: chunks [kg*4, kg*4+4)
  const int ct_ = w & 7;               // col-tile
  const int l15 = lane & 15;
  const int lq = lane >> 4;
  const int n0 = blockIdx.x * 32;
  const int rx = (l15 & 7) << 4;

  // A staging: 1024 thr = 32 rows x 32 col-groups; pair {c, c+4} per iter.
  const int srow = t >> 5;             // 0..31
  const int scf = t & 31;              // fp32 cols scf*4 + j*128
  const float* ap = inp + (size_t)(n0 + srow) * 4096 + scf * 4;
  const int sx = (srow & 7) << 4;

  f32x4 accO[2] = {}, acc8[2] = {};
  float4 av[2][4];

  const uint4* wown = W1p + (size_t)(ct_ * 128) * 64 + lane;
  const uint4* w8b  = W1p + (size_t)(8 * 128) * 64 + lane;

  // ---- prologue: stage pair {0, 4}
#pragma unroll
  for (int g = 0; g < 2; ++g)
#pragma unroll
    for (int j = 0; j < 4; ++j)
      av[g][j] = *(const float4*)(ap + (size_t)(g * 4) * 512 + j * 128);
#pragma unroll
  for (int g = 0; g < 2; ++g) {
    char* d2 = Ab + g * 32768 + srow * 1024;
#pragma unroll
    for (int j = 0; j < 4; ++j) {
      uint2 u; u.x = pk2(av[g][j].x, av[g][j].y); u.y = pk2(av[g][j].z, av[g][j].w);
      *(uint2*)(d2 + ((scf * 8 + j * 256) ^ sx)) = u;
    }
  }
  __syncthreads();

  for (int c = 0; c < 4; ++c) {
    if (c < 3) {  // prefetch next pair {c+1, c+5} into registers
#pragma unroll
      for (int g = 0; g < 2; ++g)
#pragma unroll
        for (int j = 0; j < 4; ++j)
          av[g][j] = *(const float4*)(ap + (size_t)(g * 4 + c + 1) * 512 + j * 128);
    }
    const int ck = kg * 4 + c;         // this wave's K-chunk
    const char* A0 = Ab + kg * 32768;
#pragma unroll
    for (int ks = 0; ks < 16; ++ks) {
      bf16x8 b = __builtin_bit_cast(bf16x8, wown[(size_t)(ck * 16 + ks) * 64]);
      bf16x8 a0 = *(const bf16x8*)(A0 + l15 * 1024 + ((ks * 64 + lq * 16) ^ rx));
      bf16x8 a1 = *(const bf16x8*)(A0 + (16 + l15) * 1024 + ((ks * 64 + lq * 16) ^ rx));
      accO[0] = mfma16(a0, b, accO[0]);
      accO[1] = mfma16(a1, b, accO[1]);
    }
#pragma unroll
    for (int ii = 0; ii < 2; ++ii) {   // gating tile-8, ks split by col-tile
      const int ks8 = ct_ + ii * 8;
      bf16x8 b8 = __builtin_bit_cast(bf16x8, w8b[(size_t)(ck * 16 + ks8) * 64]);
      bf16x8 a0 = *(const bf16x8*)(A0 + l15 * 1024 + ((ks8 * 64 + lq * 16) ^ rx));
      bf16x8 a1 = *(const bf16x8*)(A0 + (16 + l15) * 1024 + ((ks8 * 64 + lq * 16) ^ rx));
      acc8[0] = mfma16(a0, b8, acc8[0]);
      acc8[1] = mfma16(a1, b8, acc8[1]);
    }
    if (c < 3) {
      LDS_BARRIER();                   // all reads of Ab done (lgkm only:
                                       // av global prefetch stays in flight)
#pragma unroll
      for (int g = 0; g < 2; ++g) {
        char* d2 = Ab + g * 32768 + srow * 1024;
#pragma unroll
        for (int j = 0; j < 4; ++j) {
          uint2 u; u.x = pk2(av[g][j].x, av[g][j].y); u.y = pk2(av[g][j].z, av[g][j].w);
          *(uint2*)(d2 + ((scf * 8 + j * 256) ^ sx)) = u;
        }
      }
    }
    LDS_BARRIER();                     // staged writes visible / final fence
  }

  // ---- reductions: accO pair-sum (w, w+8) + acc8 16-way (reuse A region)
  *(f32x4*)(Ab + (size_t)((w * 2 + 0) * 64 + lane) * 16) = accO[0];
  *(f32x4*)(Ab + (size_t)((w * 2 + 1) * 64 + lane) * 16) = accO[1];
  *(f32x4*)(Ab + 32768 + (size_t)((w * 2 + 0) * 64 + lane) * 16) = acc8[0];
  *(f32x4*)(Ab + 32768 + (size_t)((w * 2 + 1) * 64 + lane) * 16) = acc8[1];
  __syncthreads();
  f32x4 hO[2] = {};
  if (w < 8) {
#pragma unroll
    for (int tt = 0; tt < 2; ++tt) {
      f32x4 x = *(const f32x4*)(Ab + (size_t)((w * 2 + tt) * 64 + lane) * 16);
      f32x4 y = *(const f32x4*)(Ab + (size_t)(((w + 8) * 2 + tt) * 64 + lane) * 16);
#pragma unroll
      for (int r_ = 0; r_ < 4; ++r_) hO[tt][r_] = x[r_] + y[r_];
    }
  }
  if (t < 512) {  // gating scores: 32 tok x 16 cols
    const int tok = t >> 4, col = t & 15;
    const int tt = tok >> 4, lq_ = (tok >> 2) & 3, r_ = tok & 3;
    float sv = 0.f;
#pragma unroll
    for (int w2 = 0; w2 < 16; ++w2)
      sv += *(const float*)(Ab + 32768 +
            (size_t)((w2 * 2 + tt) * 64 + lq_ * 16 + col) * 16 + r_ * 4);
    scores[tok * 16 + col] = sv;
  }
  __syncthreads();
  if (t < 32) {
    float l_[9];
#pragma unroll
    for (int e = 0; e < 9; ++e) l_[e] = scores[t * 16 + e];
    float mx = -3.4e38f;
#pragma unroll
    for (int e = 0; e < 8; ++e) { l_[e] += rb[e]; mx = fmaxf(mx, l_[e]); }
    float g[8], s = 0.f;
#pragma unroll
    for (int e = 0; e < 8; ++e) { g[e] = __expf(l_[e] - mx); s += g[e]; }
    const float thr = 0.125f / (1.f + __expf(-(l_[8] + tb[0])));
    const float inv = 1.f / s;
    float wv[8], ws = 0.f;
#pragma unroll
    for (int e = 0; e < 8; ++e) { wv[e] = fmaxf(g[e] * inv - thr, 0.f); ws += wv[e]; }
    const float wn = (ws == 0.f) ? 1.f : ws;
#pragma unroll
    for (int e = 0; e < 8; ++e) wgt[t * 8 + e] = wv[e] / wn;
  }
  __syncthreads();
  // weighted h -> whl (wave w<8 == expert w), swizzled by token
  if (w < 8) {
#pragma unroll
    for (int tt = 0; tt < 2; ++tt)
#pragma unroll
      for (int r_ = 0; r_ < 4; ++r_) {
        const int tok = tt * 16 + lq * 4 + r_;
        *(unsigned short*)(whl + tok * 256 + (((w * 16 + l15) * 2) ^ ((tok & 7) << 4))) =
            (unsigned short)bfbits(hO[tt][r_] * wgt[tok * 8 + w]);
      }
  }
  __syncthreads();
  // coalesced wh write: rows copied byte-verbatim (swizzle kept; n0%32==0)
  if (t < 512) {
    const int row = t >> 4, seg = t & 15;
    ((uint4*)(wh + (size_t)(n0 + row) * 128))[seg] =
        ((const uint4*)(whl + row * 256))[seg];
  }
}

// ---------------- k2_out: out[256 tok][128 col] per block, grid 1024, 512
// thr. B2p slice staged once to LDS; swizzled Ob bounce -> 128B-contiguous
// nontemporal stores; bounce barriers lgkm-only so stores keep streaming.
__global__ __launch_bounds__(512, 4) void k2_out(
    const unsigned short* __restrict__ wh, const uint4* __restrict__ B2p,
    float* __restrict__ out) {
  __shared__ __align__(16) char Bl[32768];
  __shared__ __align__(16) char Ob[32768];
  const int t = threadIdx.x, lane = t & 63, w = t >> 6;
  const int l15 = lane & 15, lq = lane >> 4;
  const int bid = blockIdx.x;
  const int tokg = bid >> 5, colg = bid & 31;
  const int n0 = tokg * 256, c0 = colg * 128;

  {  // stage B slice: 8 ct x 4 ks x 64 lanes x 16B = 32 KB, linear
    const uint4* src = B2p + (size_t)(colg * 32) * 64;
#pragma unroll
    for (int i = 0; i < 4; ++i)
      __builtin_amdgcn_global_load_lds((gp_t)(const void*)(src + i * 512 + t),
          (lp_t)(void*)(Bl + (i * 512 + w * 64) * 16), 16, 0, 0);
  }
  __syncthreads();  // vmcnt drain required (global_load_lds) — keep full sync

  const int srow = t >> 3, sseg = t & 7;       // store map: 64 rows x 8 segs
  const int swz = (srow & 7) << 4;

#pragma unroll
  for (int tt = 0; tt < 2; ++tt) {
    const int tok = n0 + tt * 128 + w * 16 + l15;
    bf16x8 pa[4];
    const uint4* whu = (const uint4*)wh + (size_t)tok * 16;
#pragma unroll
    for (int ks = 0; ks < 4; ++ks)
      pa[ks] = __builtin_bit_cast(bf16x8, whu[(ks * 4 + lq) ^ (l15 & 7)]);
    f32x4 acc[8] = {};
#pragma unroll
    for (int ct = 0; ct < 8; ++ct)
#pragma unroll
      for (int ks = 0; ks < 4; ++ks) {
        bf16x8 b = *(const bf16x8*)(Bl + (size_t)((ct * 4 + ks) * 64 + lane) * 16);
        acc[ct] = mfma16(b, pa[ks], acc[ct]);  // swapped: 4 consecutive cols/lane
      }
#pragma unroll
    for (int sr = 0; sr < 2; ++sr) {
      if ((w >> 2) == sr) {
        const int tl = (w & 3) * 16 + l15;     // 0..63
        char* d = Ob + tl * 512;
#pragma unroll
        for (int ct = 0; ct < 8; ++ct)
          *(f32x4*)(d + ((ct * 64 + lq * 16) ^ ((tl & 7) << 4))) = acc[ct];
      }
      LDS_BARRIER();                           // Ob writes visible; global
                                               // stores keep streaming
      {
        float* op = out + (size_t)(n0 + tt * 128 + sr * 64 + srow) * 4096 + c0 + sseg * 4;
#pragma unroll
        for (int j = 0; j < 4; ++j) {
          f32x4 v = *(const f32x4*)(Ob + srow * 512 + ((sseg * 16 + j * 128) ^ swz));
          __builtin_nontemporal_store(v, (f32x4*)(op + j * 32));
        }
      }
      LDS_BARRIER();                           // Ob reads done before overwrite
    }
  }
}

extern "C" void kernel_launch(void* const* d_in, const int* in_sizes, int n_in,
                              void* d_out, int out_size, void* d_ws, size_t ws_size,
                              hipStream_t stream) {
  (void)in_sizes; (void)n_in; (void)out_size; (void)ws_size;
  const float* inp      = (const float*)d_in[0];
  const float* router_w = (const float*)d_in[1];
  const float* router_b = (const float*)d_in[2];
  const float* thr_w    = (const float*)d_in[3];
  const float* thr_b    = (const float*)d_in[4];
  const float* lora_A   = (const float*)d_in[5];
  const float* lora_B   = (const float*)d_in[6];
  float* out = (float*)d_out;

  char* ws = (char*)d_ws;
  uint4*          W1p = (uint4*)ws;                                // 1,179,648 B
  uint4*          B2p = (uint4*)(ws + 1179648);                    // 1,048,576 B
  unsigned short* wh  = (unsigned short*)(ws + 1179648 + 1048576); // 2,097,152 B

  pack_all<<<544, 256, 0, stream>>>(router_w, thr_w, lora_A, lora_B, W1p, B2p);
  k1_gate<<<256, 1024, 0, stream>>>(inp, W1p, router_b, thr_b, wh);
  k2_out<<<1024, 512, 0, stream>>>(wh, B2p, out);
}